// Round 1
// baseline (151.327 us; speedup 1.0000x reference)
//
#include <hip/hip_runtime.h>

// Window attention, fused: qkv GEMM -> 4-head softmax attention -> proj GEMM.
// B=4096, N=49, C=128, H=4, d=32. All intermediates in LDS (bf16), MFMA 16x16x32.

#define N_TOK 49
#define QK_STRIDE 264   // elems; 528 B rows (16B aligned, 2-way banks)
#define P_STRIDE  72    // elems; 144 B rows (16B aligned, 2-way banks)
#define VT_STRIDE 72
#define PH_SZ     (64 * P_STRIDE)      // 4608 elems per head P/O buffer
#define VT_BASE   (4 * PH_SZ)          // 18432
#define LDS_ELEMS (VT_BASE + 128 * VT_STRIDE)  // 27648 elems = 55296 B

typedef __attribute__((ext_vector_type(8))) __bf16 bf16x8;
typedef __attribute__((ext_vector_type(4))) __bf16 bf16x4;
typedef __attribute__((ext_vector_type(4))) float  f32x4;

// ---- weight pre-pack: WqkvT A-frags (49152 bf16) + Wproj B-frags (16384 bf16)
__global__ void pack_weights(const float* __restrict__ Wqkv,
                             const float* __restrict__ Wproj,
                             __bf16* __restrict__ ws) {
    int idx  = blockIdx.x * 256 + threadIdx.x;   // 65536 total
    int j    = idx & 7;
    int lane = (idx >> 3) & 63;
    int l16  = lane & 15, g = lane >> 4;
    if (idx < 49152) {
        int frag = idx >> 9;
        int mt = frag >> 2, ks = frag & 3;
        int m = mt * 16 + l16;            // outch (row of WqkvT)
        int k = ks * 32 + g * 8 + j;      // inch
        ws[idx] = (__bf16)Wqkv[k * 384 + m];
    } else {
        int i2 = idx - 49152;
        int frag = i2 >> 9;
        int nt = frag >> 2, ks = frag & 3;
        int n = nt * 16 + l16;            // outch
        int k = ks * 32 + g * 8 + j;      // inch
        ws[idx] = (__bf16)Wproj[k * 128 + n];
    }
}

__global__ __launch_bounds__(256, 2)
void fused_win_attn(const float* __restrict__ x,
                    const float* __restrict__ bqkv,
                    const float* __restrict__ bproj,
                    const __bf16* __restrict__ wpack,
                    float* __restrict__ out) {
    __shared__ __bf16 lds[LDS_ELEMS];

    const int tid  = threadIdx.x;
    const int w    = tid >> 6;       // wave id == n-tile (phase1/3) == head (phase2)
    const int lane = tid & 63;
    const int l16  = lane & 15;
    const int g    = lane >> 4;
    const int b    = blockIdx.x;
    const float* xb = x + (size_t)b * (N_TOK * 128);

    // ============ Phase 1: qkvT = WqkvT @ xT  (M=384, N=64 tokens, K=128) ====
    const int token_b = 16 * w + l16;
    const bool tv = token_b < N_TOK;
    bf16x8 xfrag[4];
    #pragma unroll
    for (int ks = 0; ks < 4; ++ks) {
        f32x4 lo = {0.f, 0.f, 0.f, 0.f}, hi = {0.f, 0.f, 0.f, 0.f};
        if (tv) {
            const float* p = xb + token_b * 128 + ks * 32 + g * 8;
            lo = *(const f32x4*)p;
            hi = *(const f32x4*)(p + 4);
        }
        bf16x8 f;
        f[0] = (__bf16)lo[0]; f[1] = (__bf16)lo[1]; f[2] = (__bf16)lo[2]; f[3] = (__bf16)lo[3];
        f[4] = (__bf16)hi[0]; f[5] = (__bf16)hi[1]; f[6] = (__bf16)hi[2]; f[7] = (__bf16)hi[3];
        xfrag[ks] = f;
    }

    f32x4 acc[24];
    #pragma unroll
    for (int mt = 0; mt < 24; ++mt) acc[mt] = (f32x4){0.f, 0.f, 0.f, 0.f};
    #pragma unroll
    for (int ks = 0; ks < 4; ++ks) {
        #pragma unroll
        for (int mt = 0; mt < 24; ++mt) {
            bf16x8 af = *(const bf16x8*)(wpack + ((mt * 4 + ks) * 64 + lane) * 8);
            acc[mt] = __builtin_amdgcn_mfma_f32_16x16x32_bf16(af, xfrag[ks], acc[mt], 0, 0, 0);
        }
    }
    // epilogue: D m = outch = 16mt+4g+i, n = token = 16w+l16
    #pragma unroll
    for (int mt = 0; mt < 24; ++mt) {
        const int och0 = mt * 16 + g * 4;
        float v0 = acc[mt][0] + bqkv[och0 + 0];
        float v1 = acc[mt][1] + bqkv[och0 + 1];
        float v2 = acc[mt][2] + bqkv[och0 + 2];
        float v3 = acc[mt][3] + bqkv[och0 + 3];
        if (mt < 16) {
            // Q,K -> qk_lds[token][outch] (channel-contiguous, b64 packed)
            bf16x4 pk = { (__bf16)v0, (__bf16)v1, (__bf16)v2, (__bf16)v3 };
            *(bf16x4*)&lds[token_b * QK_STRIDE + och0] = pk;
        } else {
            // V -> vT[outch-256][token] (token-contiguous for PV B-operand)
            const int vr = och0 - 256;
            lds[VT_BASE + (vr + 0) * VT_STRIDE + token_b] = (__bf16)v0;
            lds[VT_BASE + (vr + 1) * VT_STRIDE + token_b] = (__bf16)v1;
            lds[VT_BASE + (vr + 2) * VT_STRIDE + token_b] = (__bf16)v2;
            lds[VT_BASE + (vr + 3) * VT_STRIDE + token_b] = (__bf16)v3;
        }
    }
    __syncthreads();

    // ============ Phase 2a: S^T = K_h @ Q_h^T  (per wave = per head) =========
    const int h = w;
    bf16x8 kf[4], qf[4];
    #pragma unroll
    for (int t = 0; t < 4; ++t) {
        kf[t] = *(const bf16x8*)&lds[(l16 + 16 * t) * QK_STRIDE + 128 + 32 * h + 8 * g];
        qf[t] = *(const bf16x8*)&lds[(l16 + 16 * t) * QK_STRIDE + 32 * h + 8 * g];
    }
    f32x4 s[4][4];
    #pragma unroll
    for (int mt = 0; mt < 4; ++mt)
        #pragma unroll
        for (int nt = 0; nt < 4; ++nt)
            s[mt][nt] = __builtin_amdgcn_mfma_f32_16x16x32_bf16(
                kf[mt], qf[nt], (f32x4){0.f, 0.f, 0.f, 0.f}, 0, 0, 0);

    // softmax over keys (= M dim of S^T); lane holds keys {16mt+4g+i} for q=l16+16nt
    constexpr float SC = 0.08838834764831845f * 1.4426950408889634f;  // scale*log2e
    #pragma unroll
    for (int nt = 0; nt < 4; ++nt) {
        float mx = -1e30f;
        #pragma unroll
        for (int mt = 0; mt < 4; ++mt)
            #pragma unroll
            for (int i = 0; i < 4; ++i) {
                int key = 16 * mt + 4 * g + i;
                if (key < N_TOK) mx = fmaxf(mx, s[mt][nt][i]);
            }
        mx = fmaxf(mx, __shfl_xor(mx, 16));
        mx = fmaxf(mx, __shfl_xor(mx, 32));
        float sum = 0.f;
        #pragma unroll
        for (int mt = 0; mt < 4; ++mt)
            #pragma unroll
            for (int i = 0; i < 4; ++i) {
                int key = 16 * mt + 4 * g + i;
                float p = (key < N_TOK) ? exp2f((s[mt][nt][i] - mx) * SC) : 0.f;
                s[mt][nt][i] = p;
                sum += p;
            }
        sum += __shfl_xor(sum, 16);
        sum += __shfl_xor(sum, 32);
        float r = 1.f / sum;
        #pragma unroll
        for (int mt = 0; mt < 4; ++mt)
            #pragma unroll
            for (int i = 0; i < 4; ++i) s[mt][nt][i] *= r;
    }
    __syncthreads();  // all waves done reading Q/K before P overwrites the region

    // ============ Phase 2b: P write + O^T = V^T @ P^T =========================
    // P stored [q][key] (key-contiguous); lane's 4 regs = 4 consecutive keys -> b64
    #pragma unroll
    for (int mt = 0; mt < 4; ++mt)
        #pragma unroll
        for (int nt = 0; nt < 4; ++nt) {
            bf16x4 pk = { (__bf16)s[mt][nt][0], (__bf16)s[mt][nt][1],
                          (__bf16)s[mt][nt][2], (__bf16)s[mt][nt][3] };
            *(bf16x4*)&lds[h * PH_SZ + (l16 + 16 * nt) * P_STRIDE + 16 * mt + 4 * g] = pk;
        }

    f32x4 o[2][4];
    #pragma unroll
    for (int mt = 0; mt < 2; ++mt)
        #pragma unroll
        for (int nt = 0; nt < 4; ++nt) o[mt][nt] = (f32x4){0.f, 0.f, 0.f, 0.f};
    #pragma unroll
    for (int ks = 0; ks < 2; ++ks) {
        bf16x8 vf[2], pf[4];
        #pragma unroll
        for (int mt = 0; mt < 2; ++mt)
            vf[mt] = *(const bf16x8*)&lds[VT_BASE + (32 * h + 16 * mt + l16) * VT_STRIDE + 32 * ks + 8 * g];
        #pragma unroll
        for (int nt = 0; nt < 4; ++nt)
            pf[nt] = *(const bf16x8*)&lds[h * PH_SZ + (l16 + 16 * nt) * P_STRIDE + 32 * ks + 8 * g];
        #pragma unroll
        for (int mt = 0; mt < 2; ++mt)
            #pragma unroll
            for (int nt = 0; nt < 4; ++nt)
                o[mt][nt] = __builtin_amdgcn_mfma_f32_16x16x32_bf16(vf[mt], pf[nt], o[mt][nt], 0, 0, 0);
    }
    // O row-major per head, aliased over own P buffer (all P reads done, same wave)
    #pragma unroll
    for (int mt = 0; mt < 2; ++mt)
        #pragma unroll
        for (int nt = 0; nt < 4; ++nt) {
            bf16x4 pk = { (__bf16)o[mt][nt][0], (__bf16)o[mt][nt][1],
                          (__bf16)o[mt][nt][2], (__bf16)o[mt][nt][3] };
            *(bf16x4*)&lds[h * PH_SZ + (l16 + 16 * nt) * P_STRIDE + 16 * mt + 4 * g] = pk;
        }
    __syncthreads();

    // ============ Phase 3: out = O @ Wproj + bproj ============================
    // A-frag: O[token][inch], inch = 32ks+8g+j -> head buffer ks, dd = 8g+j
    bf16x8 of[4];
    #pragma unroll
    for (int ks = 0; ks < 4; ++ks)
        of[ks] = *(const bf16x8*)&lds[ks * PH_SZ + (l16 + 16 * w) * P_STRIDE + 8 * g];
    const __bf16* bp = wpack + 49152;
    f32x4 po[8];
    #pragma unroll
    for (int nt = 0; nt < 8; ++nt) {
        f32x4 a = {0.f, 0.f, 0.f, 0.f};
        #pragma unroll
        for (int ks = 0; ks < 4; ++ks) {
            bf16x8 bf = *(const bf16x8*)(bp + ((nt * 4 + ks) * 64 + lane) * 8);
            a = __builtin_amdgcn_mfma_f32_16x16x32_bf16(of[ks], bf, a, 0, 0, 0);
        }
        po[nt] = a;
    }
    #pragma unroll
    for (int nt = 0; nt < 8; ++nt) {
        const int och = l16 + 16 * nt;
        const float bias = bproj[och];
        #pragma unroll
        for (int i = 0; i < 4; ++i) {
            const int token = 16 * w + 4 * g + i;
            if (token < N_TOK)
                out[((size_t)b * N_TOK + token) * 128 + och] = po[nt][i] + bias;
        }
    }
}

extern "C" void kernel_launch(void* const* d_in, const int* in_sizes, int n_in,
                              void* d_out, int out_size, void* d_ws, size_t ws_size,
                              hipStream_t stream) {
    const float* x     = (const float*)d_in[0];
    const float* Wqkv  = (const float*)d_in[1];
    const float* bqkv  = (const float*)d_in[2];
    const float* Wproj = (const float*)d_in[3];
    const float* bproj = (const float*)d_in[4];
    __bf16* ws  = (__bf16*)d_ws;
    float* outp = (float*)d_out;

    pack_weights<<<256, 256, 0, stream>>>(Wqkv, Wproj, ws);
    fused_win_attn<<<4096, 256, 0, stream>>>(x, bqkv, bproj, ws, outp);
}

// Round 2
// 116.335 us; speedup vs baseline: 1.3008x; 1.3008x over previous
//
#include <hip/hip_runtime.h>

// Window attention, fused, head-split: wave w owns head w's Q/K/V channels for
// all 64 (padded) tokens -> phases 1..2 are wave-private, ONE barrier total.
// B=4096, N=49, C=128, H=4, d=32. MFMA 16x16x32 bf16. LDS 48KB, 3 blocks/CU.

#define N_TOK 49

typedef __attribute__((ext_vector_type(8))) __bf16 bf16x8;
typedef __attribute__((ext_vector_type(4))) __bf16 bf16x4;
typedef __attribute__((ext_vector_type(4))) float  f32x4;

// ---- weight pre-pack: WqkvT A-frags (49152 bf16) + Wproj B-frags (16384 bf16)
__global__ void pack_weights(const float* __restrict__ Wqkv,
                             const float* __restrict__ Wproj,
                             __bf16* __restrict__ ws) {
    int idx  = blockIdx.x * 256 + threadIdx.x;   // 65536 total
    int j    = idx & 7;
    int lane = (idx >> 3) & 63;
    int l16  = lane & 15, g = lane >> 4;
    if (idx < 49152) {
        int frag = idx >> 9;
        int mt = frag >> 2, ks = frag & 3;
        int m = mt * 16 + l16;            // outch (row of WqkvT)
        int k = ks * 32 + g * 8 + j;      // inch
        ws[idx] = (__bf16)Wqkv[k * 384 + m];
    } else {
        int i2 = idx - 49152;
        int frag = i2 >> 9;
        int nt = frag >> 2, ks = frag & 3;
        int n = nt * 16 + l16;            // outch
        int k = ks * 32 + g * 8 + j;      // inch
        ws[idx] = (__bf16)Wproj[k * 128 + n];
    }
}

// Per-head LDS (12288 B): region A (8192 B) holds QK[tok64][ch64] then is
// reused for P[q64][key64] then O[q64][ch32]; region V (4096 B) = V^T[ch32][tok64].
// All XOR-swizzled on the 16B block index -> ~2-way banks for b64/b128 ops.
__device__ __forceinline__ int qk_off(int tok, int ch) {        // also P
    return tok * 128 + ((((ch >> 3) ^ (tok & 7))) << 4) + ((ch & 7) << 1);
}
__device__ __forceinline__ int o_off(int q, int ch) {           // 32-ch rows
    return q * 64 + ((((ch >> 3) ^ (q & 3))) << 4) + ((ch & 7) << 1);
}
__device__ __forceinline__ int vt_off(int ch, int tok) {
    return 8192 + ch * 128 + ((((tok >> 3) ^ (ch & 7))) << 4) + ((tok & 7) << 1);
}

__global__ __launch_bounds__(256, 3)
void fused_win_attn(const float* __restrict__ x,
                    const float* __restrict__ bqkv,
                    const float* __restrict__ bproj,
                    const __bf16* __restrict__ wpack,
                    float* __restrict__ out) {
    __shared__ __align__(16) char smem[49152];

    const int tid  = threadIdx.x;
    const int w    = tid >> 6;       // wave id == head id (phases 1-2)
    const int lane = tid & 63;
    const int l16  = lane & 15;
    const int g    = lane >> 4;
    const int b    = blockIdx.x;
    const float* xb = x + (size_t)b * (N_TOK * 128);
    char* hB = smem + w * 12288;

    // ===== Phase 1: this head's 96 channels (Q,K,V) x all 64 tokens, K=128 ==
    f32x4 acc[6][4];
    #pragma unroll
    for (int m = 0; m < 6; ++m)
        #pragma unroll
        for (int nt = 0; nt < 4; ++nt) acc[m][nt] = (f32x4){0.f, 0.f, 0.f, 0.f};

    #pragma unroll
    for (int ks = 0; ks < 4; ++ks) {
        bf16x8 xf[4];
        #pragma unroll
        for (int nt = 0; nt < 4; ++nt) {
            int tok = 16 * nt + l16;
            f32x4 lo = {0.f,0.f,0.f,0.f}, hi = {0.f,0.f,0.f,0.f};
            if (tok < N_TOK) {
                const float* p = xb + tok * 128 + ks * 32 + g * 8;
                lo = *(const f32x4*)p;
                hi = *(const f32x4*)(p + 4);
            }
            bf16x8 f;
            f[0]=(__bf16)lo[0]; f[1]=(__bf16)lo[1]; f[2]=(__bf16)lo[2]; f[3]=(__bf16)lo[3];
            f[4]=(__bf16)hi[0]; f[5]=(__bf16)hi[1]; f[6]=(__bf16)hi[2]; f[7]=(__bf16)hi[3];
            xf[nt] = f;
        }
        #pragma unroll
        for (int m = 0; m < 6; ++m) {
            // global m-tiles for head w: Q: 2w,2w+1  K: 8+2w,8+2w+1  V: 16+2w,16+2w+1
            int mtg = (m < 2) ? (2 * w + m) : (m < 4) ? (8 + 2 * w + m - 2)
                                                      : (16 + 2 * w + m - 4);
            bf16x8 af = *(const bf16x8*)(wpack + ((mtg * 4 + ks) * 64 + lane) * 8);
            #pragma unroll
            for (int nt = 0; nt < 4; ++nt)
                acc[m][nt] = __builtin_amdgcn_mfma_f32_16x16x32_bf16(af, xf[nt], acc[m][nt], 0, 0, 0);
        }
    }
    // epilogue: D m = och = 4g+i within tile, n = token = 16nt+l16
    #pragma unroll
    for (int m = 0; m < 6; ++m) {
        int ochb = (m < 2) ? (32 * w + 16 * m) : (m < 4) ? (128 + 32 * w + 16 * (m - 2))
                                                         : (256 + 32 * w + 16 * (m - 4));
        f32x4 bias = *(const f32x4*)(bqkv + ochb + 4 * g);
        #pragma unroll
        for (int nt = 0; nt < 4; ++nt) {
            int tok = 16 * nt + l16;
            float v0 = acc[m][nt][0] + bias[0];
            float v1 = acc[m][nt][1] + bias[1];
            float v2 = acc[m][nt][2] + bias[2];
            float v3 = acc[m][nt][3] + bias[3];
            if (m < 4) {
                // Q -> local ch 0..31, K -> local ch 32..63, packed b64
                bf16x4 pk = {(__bf16)v0, (__bf16)v1, (__bf16)v2, (__bf16)v3};
                *(bf16x4*)(hB + qk_off(tok, 16 * m + 4 * g)) = pk;
            } else {
                int vch = 16 * (m - 4) + 4 * g;   // V^T[ch][tok], scalar writes
                *(__bf16*)(hB + vt_off(vch + 0, tok)) = (__bf16)v0;
                *(__bf16*)(hB + vt_off(vch + 1, tok)) = (__bf16)v1;
                *(__bf16*)(hB + vt_off(vch + 2, tok)) = (__bf16)v2;
                *(__bf16*)(hB + vt_off(vch + 3, tok)) = (__bf16)v3;
            }
        }
    }
    // wave-private from here: LDS ops of a wave execute in order, no barrier.

    // ===== Phase 2a: S^T = K_h @ Q_h^T  (M=64 keys, N=64 q, K=32 ch) ========
    bf16x8 kf[4], qf[4];
    #pragma unroll
    for (int t = 0; t < 4; ++t) {
        kf[t] = *(const bf16x8*)(hB + qk_off(16 * t + l16, 32 + 8 * g));
        qf[t] = *(const bf16x8*)(hB + qk_off(16 * t + l16, 8 * g));
    }
    f32x4 s[4][4];
    #pragma unroll
    for (int mt = 0; mt < 4; ++mt)
        #pragma unroll
        for (int nt = 0; nt < 4; ++nt)
            s[mt][nt] = __builtin_amdgcn_mfma_f32_16x16x32_bf16(
                kf[mt], qf[nt], (f32x4){0.f, 0.f, 0.f, 0.f}, 0, 0, 0);

    // softmax over keys; lane holds keys {16mt+4g+i} for q = 16nt+l16
    constexpr float SC = 0.08838834764831845f * 1.4426950408889634f;  // scale*log2e
    #pragma unroll
    for (int nt = 0; nt < 4; ++nt) {
        float mx = -1e30f;
        #pragma unroll
        for (int mt = 0; mt < 4; ++mt)
            #pragma unroll
            for (int i = 0; i < 4; ++i) {
                int key = 16 * mt + 4 * g + i;
                if (key < N_TOK) mx = fmaxf(mx, s[mt][nt][i]);
            }
        mx = fmaxf(mx, __shfl_xor(mx, 16));
        mx = fmaxf(mx, __shfl_xor(mx, 32));
        float sum = 0.f;
        #pragma unroll
        for (int mt = 0; mt < 4; ++mt)
            #pragma unroll
            for (int i = 0; i < 4; ++i) {
                int key = 16 * mt + 4 * g + i;
                float p = (key < N_TOK) ? exp2f((s[mt][nt][i] - mx) * SC) : 0.f;
                s[mt][nt][i] = p;
                sum += p;
            }
        sum += __shfl_xor(sum, 16);
        sum += __shfl_xor(sum, 32);
        float r = 1.f / sum;
        #pragma unroll
        for (int mt = 0; mt < 4; ++mt)
            #pragma unroll
            for (int i = 0; i < 4; ++i) s[mt][nt][i] *= r;
    }

    // P[q][key] over the QK region (this wave already consumed Q/K into regs)
    #pragma unroll
    for (int mt = 0; mt < 4; ++mt)
        #pragma unroll
        for (int nt = 0; nt < 4; ++nt) {
            bf16x4 pk = {(__bf16)s[mt][nt][0], (__bf16)s[mt][nt][1],
                         (__bf16)s[mt][nt][2], (__bf16)s[mt][nt][3]};
            *(bf16x4*)(hB + qk_off(16 * nt + l16, 16 * mt + 4 * g)) = pk;
        }

    // ===== Phase 2b: O^T = V_h^T @ P^T  (M=32 ch, N=64 q, K=64 keys) ========
    bf16x8 vf[2][2], pf[4][2];
    #pragma unroll
    for (int ks = 0; ks < 2; ++ks) {
        #pragma unroll
        for (int m = 0; m < 2; ++m)
            vf[m][ks] = *(const bf16x8*)(hB + vt_off(16 * m + l16, 32 * ks + 8 * g));
        #pragma unroll
        for (int nt = 0; nt < 4; ++nt)
            pf[nt][ks] = *(const bf16x8*)(hB + qk_off(16 * nt + l16, 32 * ks + 8 * g));
    }
    f32x4 o[2][4];
    #pragma unroll
    for (int m = 0; m < 2; ++m)
        #pragma unroll
        for (int nt = 0; nt < 4; ++nt) o[m][nt] = (f32x4){0.f, 0.f, 0.f, 0.f};
    #pragma unroll
    for (int ks = 0; ks < 2; ++ks)
        #pragma unroll
        for (int m = 0; m < 2; ++m)
            #pragma unroll
            for (int nt = 0; nt < 4; ++nt)
                o[m][nt] = __builtin_amdgcn_mfma_f32_16x16x32_bf16(
                    vf[m][ks], pf[nt][ks], o[m][nt], 0, 0, 0);
    // O[q][ch32] aliases P rows 0..31 — all pf reads already landed in regs.
    #pragma unroll
    for (int m = 0; m < 2; ++m)
        #pragma unroll
        for (int nt = 0; nt < 4; ++nt) {
            bf16x4 pk = {(__bf16)o[m][nt][0], (__bf16)o[m][nt][1],
                         (__bf16)o[m][nt][2], (__bf16)o[m][nt][3]};
            *(bf16x4*)(hB + o_off(16 * nt + l16, 16 * m + 4 * g)) = pk;
        }
    __syncthreads();   // the only barrier: proj mixes all heads' O

    // ===== Phase 3: out = O @ Wproj + bproj; wave w owns och 32w..32w+31 ====
    f32x4 po[4][2];
    #pragma unroll
    for (int mt = 0; mt < 4; ++mt) {
        po[mt][0] = (f32x4){0.f, 0.f, 0.f, 0.f};
        po[mt][1] = (f32x4){0.f, 0.f, 0.f, 0.f};
    }
    const __bf16* bp = wpack + 49152;
    #pragma unroll
    for (int ks = 0; ks < 4; ++ks) {   // ks = inch tile = head region
        bf16x8 b0 = *(const bf16x8*)(bp + (((2 * w + 0) * 4 + ks) * 64 + lane) * 8);
        bf16x8 b1 = *(const bf16x8*)(bp + (((2 * w + 1) * 4 + ks) * 64 + lane) * 8);
        #pragma unroll
        for (int mt = 0; mt < 4; ++mt) {
            bf16x8 a = *(const bf16x8*)(smem + ks * 12288 + o_off(16 * mt + l16, 8 * g));
            po[mt][0] = __builtin_amdgcn_mfma_f32_16x16x32_bf16(a, b0, po[mt][0], 0, 0, 0);
            po[mt][1] = __builtin_amdgcn_mfma_f32_16x16x32_bf16(a, b1, po[mt][1], 0, 0, 0);
        }
    }
    #pragma unroll
    for (int ntp = 0; ntp < 2; ++ntp) {
        const int och = 16 * (2 * w + ntp) + l16;
        const float bias = bproj[och];
        #pragma unroll
        for (int mt = 0; mt < 4; ++mt)
            #pragma unroll
            for (int i = 0; i < 4; ++i) {
                int tok = 16 * mt + 4 * g + i;
                if (tok < N_TOK)
                    out[((size_t)b * N_TOK + tok) * 128 + och] = po[mt][ntp][i] + bias;
            }
    }
}

extern "C" void kernel_launch(void* const* d_in, const int* in_sizes, int n_in,
                              void* d_out, int out_size, void* d_ws, size_t ws_size,
                              hipStream_t stream) {
    const float* x     = (const float*)d_in[0];
    const float* Wqkv  = (const float*)d_in[1];
    const float* bqkv  = (const float*)d_in[2];
    const float* Wproj = (const float*)d_in[3];
    const float* bproj = (const float*)d_in[4];
    __bf16* ws  = (__bf16*)d_ws;
    float* outp = (float*)d_out;

    pack_weights<<<256, 256, 0, stream>>>(Wqkv, Wproj, ws);
    fused_win_attn<<<4096, 256, 0, stream>>>(x, bqkv, bproj, ws, outp);
}

// Round 3
// 97.953 us; speedup vs baseline: 1.5449x; 1.1877x over previous
//
#include <hip/hip_runtime.h>

// Window attention, fused. Phase 1 token-split (x fetched ONCE per block),
// phases 2a/2b head-split wave-private, phase 3 och-split. 2 barriers.
// B=4096, N=49, C=128, H=4, d=32. MFMA 16x16x32 bf16. LDS 48KB, 3 blocks/CU.

#define N_TOK 49

typedef __attribute__((ext_vector_type(8))) __bf16 bf16x8;
typedef __attribute__((ext_vector_type(4))) __bf16 bf16x4;
typedef __attribute__((ext_vector_type(4))) float  f32x4;

// ---- weight pre-pack: WqkvT A-frags (49152 bf16) + Wproj B-frags (16384 bf16)
__global__ void pack_weights(const float* __restrict__ Wqkv,
                             const float* __restrict__ Wproj,
                             __bf16* __restrict__ ws) {
    int idx  = blockIdx.x * 256 + threadIdx.x;   // 65536 total
    int j    = idx & 7;
    int lane = (idx >> 3) & 63;
    int l16  = lane & 15, g = lane >> 4;
    if (idx < 49152) {
        int frag = idx >> 9;
        int mt = frag >> 2, ks = frag & 3;
        int m = mt * 16 + l16;            // outch (row of WqkvT)
        int k = ks * 32 + g * 8 + j;      // inch
        ws[idx] = (__bf16)Wqkv[k * 384 + m];
    } else {
        int i2 = idx - 49152;
        int frag = i2 >> 9;
        int nt = frag >> 2, ks = frag & 3;
        int n = nt * 16 + l16;            // outch
        int k = ks * 32 + g * 8 + j;      // inch
        ws[idx] = (__bf16)Wproj[k * 128 + n];
    }
}

// Per-head LDS (12288 B): region A (8192 B) = QK[tok64][ch64], reused as
// P[q64][key64], then O[q64][ch32] (first 4096 B); region V (4096 B) =
// V^T[ch32][tok64]. XOR-swizzled on the 16B block index.
__device__ __forceinline__ int qk_off(int tok, int ch) {        // also P
    return tok * 128 + ((((ch >> 3) ^ (tok & 7))) << 4) + ((ch & 7) << 1);
}
__device__ __forceinline__ int o_off(int q, int ch) {           // 32-ch rows
    return q * 64 + ((((ch >> 3) ^ (q & 3))) << 4) + ((ch & 7) << 1);
}
__device__ __forceinline__ int vt_off(int ch, int tok) {
    return 8192 + ch * 128 + ((((tok >> 3) ^ (ch & 7))) << 4) + ((tok & 7) << 1);
}

__global__ __launch_bounds__(256, 3)
void fused_win_attn(const float* __restrict__ x,
                    const float* __restrict__ bqkv,
                    const float* __restrict__ bproj,
                    const __bf16* __restrict__ wpack,
                    float* __restrict__ out) {
    __shared__ __align__(16) char smem[49152];

    const int tid  = threadIdx.x;
    const int w    = tid >> 6;       // wave id: token-tile (ph1), head (ph2), och (ph3)
    const int lane = tid & 63;
    const int l16  = lane & 15;
    const int g    = lane >> 4;
    const int b    = blockIdx.x;
    const float* xb = x + (size_t)b * (N_TOK * 128);

    // ===== Phase 1: qkv^T = WqkvT @ x^T; wave w owns tokens 16w..16w+15 =====
    const int T  = 16 * w + l16;
    const bool tv = T < N_TOK;
    // issue ALL x loads as one batch (8 dwordx4, HBM-cold)
    f32x4 xlo[4], xhi[4];
    #pragma unroll
    for (int ks = 0; ks < 4; ++ks) {
        xlo[ks] = (f32x4){0.f, 0.f, 0.f, 0.f};
        xhi[ks] = (f32x4){0.f, 0.f, 0.f, 0.f};
        if (tv) {
            const float* p = xb + T * 128 + ks * 32 + g * 8;
            xlo[ks] = *(const f32x4*)p;
            xhi[ks] = *(const f32x4*)(p + 4);
        }
    }
    bf16x8 xf[4];
    #pragma unroll
    for (int ks = 0; ks < 4; ++ks) {
        bf16x8 f;
        f[0]=(__bf16)xlo[ks][0]; f[1]=(__bf16)xlo[ks][1];
        f[2]=(__bf16)xlo[ks][2]; f[3]=(__bf16)xlo[ks][3];
        f[4]=(__bf16)xhi[ks][0]; f[5]=(__bf16)xhi[ks][1];
        f[6]=(__bf16)xhi[ks][2]; f[7]=(__bf16)xhi[ks][3];
        xf[ks] = f;
    }

    f32x4 acc[24];
    #pragma unroll
    for (int mt = 0; mt < 24; ++mt) acc[mt] = (f32x4){0.f, 0.f, 0.f, 0.f};
    #pragma unroll
    for (int mt = 0; mt < 24; ++mt)
        #pragma unroll
        for (int ks = 0; ks < 4; ++ks) {
            bf16x8 af = *(const bf16x8*)(wpack + ((mt * 4 + ks) * 64 + lane) * 8);
            acc[mt] = __builtin_amdgcn_mfma_f32_16x16x32_bf16(af, xf[ks], acc[mt], 0, 0, 0);
        }

    // prefetch proj B-frags now; latency hides under phases 1-epilogue + 2
    const __bf16* bp = wpack + 49152;
    bf16x8 bpf[2][4];
    #pragma unroll
    for (int ntp = 0; ntp < 2; ++ntp)
        #pragma unroll
        for (int ks = 0; ks < 4; ++ks)
            bpf[ntp][ks] = *(const bf16x8*)(bp + (((2 * w + ntp) * 4 + ks) * 64 + lane) * 8);

    // epilogue: D m = och = 16mt+4g+i, n = token = T. Invalid tokens hold
    // bias-only values (x zero-filled) -> finite garbage, masked at the end.
    #pragma unroll
    for (int mt = 0; mt < 24; ++mt) {
        const int och0 = mt * 16 + 4 * g;
        f32x4 bias = *(const f32x4*)(bqkv + och0);
        float v0 = acc[mt][0] + bias[0];
        float v1 = acc[mt][1] + bias[1];
        float v2 = acc[mt][2] + bias[2];
        float v3 = acc[mt][3] + bias[3];
        if (mt < 16) {
            // Q: head mt>>1, local ch 16*(mt&1)+4g; K: head (mt-8)>>1, local 32+...
            const int head = (mt < 8) ? (mt >> 1) : ((mt - 8) >> 1);
            const int lch  = (mt < 8) ? (16 * (mt & 1) + 4 * g)
                                      : (32 + 16 * (mt & 1) + 4 * g);
            bf16x4 pk = {(__bf16)v0, (__bf16)v1, (__bf16)v2, (__bf16)v3};
            *(bf16x4*)(smem + head * 12288 + qk_off(T, lch)) = pk;
        } else {
            const int head = (mt - 16) >> 1;
            const int vch  = 16 * (mt & 1) + 4 * g;
            char* hV = smem + head * 12288;
            *(__bf16*)(hV + vt_off(vch + 0, T)) = (__bf16)v0;
            *(__bf16*)(hV + vt_off(vch + 1, T)) = (__bf16)v1;
            *(__bf16*)(hV + vt_off(vch + 2, T)) = (__bf16)v2;
            *(__bf16*)(hV + vt_off(vch + 3, T)) = (__bf16)v3;
        }
    }
    __syncthreads();   // barrier 1: QKV complete; head w region now wave-private

    // ===== Phase 2a: S^T = K_h @ Q_h^T  (M=64 keys, N=64 q, K=32 ch) ========
    char* hB = smem + w * 12288;
    bf16x8 kf[4], qf[4];
    #pragma unroll
    for (int t = 0; t < 4; ++t) {
        kf[t] = *(const bf16x8*)(hB + qk_off(16 * t + l16, 32 + 8 * g));
        qf[t] = *(const bf16x8*)(hB + qk_off(16 * t + l16, 8 * g));
    }
    f32x4 s[4][4];
    #pragma unroll
    for (int mt = 0; mt < 4; ++mt)
        #pragma unroll
        for (int nt = 0; nt < 4; ++nt)
            s[mt][nt] = __builtin_amdgcn_mfma_f32_16x16x32_bf16(
                kf[mt], qf[nt], (f32x4){0.f, 0.f, 0.f, 0.f}, 0, 0, 0);

    // softmax over keys; lane holds keys {16mt+4g+i} for q = 16nt+l16
    constexpr float SC = 0.08838834764831845f * 1.4426950408889634f;  // scale*log2e
    #pragma unroll
    for (int nt = 0; nt < 4; ++nt) {
        float mx = -1e30f;
        #pragma unroll
        for (int mt = 0; mt < 4; ++mt)
            #pragma unroll
            for (int i = 0; i < 4; ++i) {
                int key = 16 * mt + 4 * g + i;
                if (key < N_TOK) mx = fmaxf(mx, s[mt][nt][i]);
            }
        mx = fmaxf(mx, __shfl_xor(mx, 16));
        mx = fmaxf(mx, __shfl_xor(mx, 32));
        float sum = 0.f;
        #pragma unroll
        for (int mt = 0; mt < 4; ++mt)
            #pragma unroll
            for (int i = 0; i < 4; ++i) {
                int key = 16 * mt + 4 * g + i;
                float p = (key < N_TOK) ? exp2f((s[mt][nt][i] - mx) * SC) : 0.f;
                s[mt][nt][i] = p;
                sum += p;
            }
        sum += __shfl_xor(sum, 16);
        sum += __shfl_xor(sum, 32);
        float r = 1.f / sum;
        #pragma unroll
        for (int mt = 0; mt < 4; ++mt)
            #pragma unroll
            for (int i = 0; i < 4; ++i) s[mt][nt][i] *= r;
    }

    // P[q][key] over the QK region (Q/K already consumed into regs by this wave)
    #pragma unroll
    for (int mt = 0; mt < 4; ++mt)
        #pragma unroll
        for (int nt = 0; nt < 4; ++nt) {
            bf16x4 pk = {(__bf16)s[mt][nt][0], (__bf16)s[mt][nt][1],
                         (__bf16)s[mt][nt][2], (__bf16)s[mt][nt][3]};
            *(bf16x4*)(hB + qk_off(16 * nt + l16, 16 * mt + 4 * g)) = pk;
        }

    // ===== Phase 2b: O^T = V_h^T @ P^T  (M=32 ch, N=64 q, K=64 keys) ========
    bf16x8 vf[2][2], pf[4][2];
    #pragma unroll
    for (int ks = 0; ks < 2; ++ks) {
        #pragma unroll
        for (int m = 0; m < 2; ++m)
            vf[m][ks] = *(const bf16x8*)(hB + vt_off(16 * m + l16, 32 * ks + 8 * g));
        #pragma unroll
        for (int nt = 0; nt < 4; ++nt)
            pf[nt][ks] = *(const bf16x8*)(hB + qk_off(16 * nt + l16, 32 * ks + 8 * g));
    }
    f32x4 o[2][4];
    #pragma unroll
    for (int m = 0; m < 2; ++m)
        #pragma unroll
        for (int nt = 0; nt < 4; ++nt) o[m][nt] = (f32x4){0.f, 0.f, 0.f, 0.f};
    #pragma unroll
    for (int ks = 0; ks < 2; ++ks)
        #pragma unroll
        for (int m = 0; m < 2; ++m)
            #pragma unroll
            for (int nt = 0; nt < 4; ++nt)
                o[m][nt] = __builtin_amdgcn_mfma_f32_16x16x32_bf16(
                    vf[m][ks], pf[nt][ks], o[m][nt], 0, 0, 0);
    // O[q][ch32] aliases P rows 0..31 — all pf reads already landed in regs.
    #pragma unroll
    for (int m = 0; m < 2; ++m)
        #pragma unroll
        for (int nt = 0; nt < 4; ++nt) {
            bf16x4 pk = {(__bf16)o[m][nt][0], (__bf16)o[m][nt][1],
                         (__bf16)o[m][nt][2], (__bf16)o[m][nt][3]};
            *(bf16x4*)(hB + o_off(16 * nt + l16, 16 * m + 4 * g)) = pk;
        }
    __syncthreads();   // barrier 2: proj mixes all heads' O

    // ===== Phase 3: out = O @ Wproj + bproj; wave w owns och 32w..32w+31 ====
    f32x4 po[4][2];
    #pragma unroll
    for (int mt = 0; mt < 4; ++mt) {
        po[mt][0] = (f32x4){0.f, 0.f, 0.f, 0.f};
        po[mt][1] = (f32x4){0.f, 0.f, 0.f, 0.f};
    }
    #pragma unroll
    for (int ks = 0; ks < 4; ++ks) {   // ks = inch tile = head region
        #pragma unroll
        for (int mt = 0; mt < 4; ++mt) {
            bf16x8 a = *(const bf16x8*)(smem + ks * 12288 + o_off(16 * mt + l16, 8 * g));
            po[mt][0] = __builtin_amdgcn_mfma_f32_16x16x32_bf16(a, bpf[0][ks], po[mt][0], 0, 0, 0);
            po[mt][1] = __builtin_amdgcn_mfma_f32_16x16x32_bf16(a, bpf[1][ks], po[mt][1], 0, 0, 0);
        }
    }
    #pragma unroll
    for (int ntp = 0; ntp < 2; ++ntp) {
        const int och = 16 * (2 * w + ntp) + l16;
        const float bias = bproj[och];
        #pragma unroll
        for (int mt = 0; mt < 4; ++mt)
            #pragma unroll
            for (int i = 0; i < 4; ++i) {
                int tok = 16 * mt + 4 * g + i;
                if (tok < N_TOK)
                    out[((size_t)b * N_TOK + tok) * 128 + och] = po[mt][ntp][i] + bias;
            }
    }
}

extern "C" void kernel_launch(void* const* d_in, const int* in_sizes, int n_in,
                              void* d_out, int out_size, void* d_ws, size_t ws_size,
                              hipStream_t stream) {
    const float* x     = (const float*)d_in[0];
    const float* Wqkv  = (const float*)d_in[1];
    const float* bqkv  = (const float*)d_in[2];
    const float* Wproj = (const float*)d_in[3];
    const float* bproj = (const float*)d_in[4];
    __bf16* ws  = (__bf16*)d_ws;
    float* outp = (float*)d_out;

    pack_weights<<<256, 256, 0, stream>>>(Wqkv, Wproj, ws);
    fused_win_attn<<<4096, 256, 0, stream>>>(x, bqkv, bproj, ws, outp);
}

// Round 4
// 96.172 us; speedup vs baseline: 1.5735x; 1.0185x over previous
//
#include <hip/hip_runtime.h>

// Window attention, fused. Phase 0: x -> LDS (bf16, swizzled, once per block).
// Phase 1 HEAD-split (each wave reads only its head's 24 weight frags -> 96KB
// L2/block instead of 384KB). Phases 2a/2b wave-private. Phase 3 och-split.
// V^T region aliases the x-buffer (x fully consumed before barrier 2).
// B=4096, N=49, C=128, H=4, d=32. MFMA 16x16x32 bf16. LDS 48KB, 3 blocks/CU.

#define N_TOK 49

typedef __attribute__((ext_vector_type(8))) __bf16 bf16x8;
typedef __attribute__((ext_vector_type(4))) __bf16 bf16x4;
typedef __attribute__((ext_vector_type(4))) float  f32x4;

// ---- weight pre-pack: WqkvT A-frags (49152 bf16) + Wproj B-frags (16384 bf16)
__global__ void pack_weights(const float* __restrict__ Wqkv,
                             const float* __restrict__ Wproj,
                             __bf16* __restrict__ ws) {
    int idx  = blockIdx.x * 256 + threadIdx.x;   // 65536 total
    int j    = idx & 7;
    int lane = (idx >> 3) & 63;
    int l16  = lane & 15, g = lane >> 4;
    if (idx < 49152) {
        int frag = idx >> 9;
        int mt = frag >> 2, ks = frag & 3;
        int m = mt * 16 + l16;            // outch (row of WqkvT)
        int k = ks * 32 + g * 8 + j;      // inch
        ws[idx] = (__bf16)Wqkv[k * 384 + m];
    } else {
        int i2 = idx - 49152;
        int frag = i2 >> 9;
        int nt = frag >> 2, ks = frag & 3;
        int n = nt * 16 + l16;            // outch
        int k = ks * 32 + g * 8 + j;      // inch
        ws[idx] = (__bf16)Wproj[k * 128 + n];
    }
}

// LDS map (49152 B):
//  [0,16384): phases 0-1: x bf16 [tok64][ch128]; after barrier 2: V^T[h][ch32][tok64]
//  [16384,49152): head h region (8192 B): QK[tok64][ch64] -> P[q64][key64] -> O[q64][ch32]
// All XOR-swizzled on the 16B-block index.
__device__ __forceinline__ int x_off(int tok, int ch) {       // 256B rows
    return tok * 256 + ((((ch >> 3) ^ (tok & 15))) << 4) + ((ch & 7) << 1);
}
__device__ __forceinline__ int vt_off(int h, int ch, int tok) {  // 128B rows
    return h * 4096 + ch * 128 + ((((tok >> 3) ^ (ch & 7))) << 4) + ((tok & 7) << 1);
}
__device__ __forceinline__ int qk_off(int h, int tok, int ch) {  // 128B rows
    return 16384 + h * 8192 + tok * 128 + ((((ch >> 3) ^ (tok & 7))) << 4) + ((ch & 7) << 1);
}
__device__ __forceinline__ int o_off(int h, int q, int ch) {     // 64B rows
    return 16384 + h * 8192 + q * 64 + ((((ch >> 3) ^ (q & 3))) << 4) + ((ch & 7) << 1);
}

__global__ __launch_bounds__(256, 3)
void fused_win_attn(const float* __restrict__ x,
                    const float* __restrict__ bqkv,
                    const float* __restrict__ bproj,
                    const __bf16* __restrict__ wpack,
                    float* __restrict__ out) {
    __shared__ __align__(16) char smem[49152];

    const int tid  = threadIdx.x;
    const int w    = tid >> 6;       // wave id: head (ph1,2), och-tile pair (ph3)
    const int lane = tid & 63;
    const int l16  = lane & 15;
    const int g    = lane >> 4;
    const int b    = blockIdx.x;
    const float* xb = x + (size_t)b * (N_TOK * 128);

    // ===== Phase 0: x (fp32 HBM) -> bf16 swizzled LDS; rows 49..63 zeroed ====
    #pragma unroll
    for (int it = 0; it < 8; ++it) {
        int idx = tid + it * 256;               // float4 index, 2048 total
        int tok = idx >> 5, c4 = (idx & 31) << 2;
        f32x4 v = (f32x4){0.f, 0.f, 0.f, 0.f};
        if (idx < N_TOK * 32) v = *(const f32x4*)(xb + idx * 4);
        bf16x4 pk = {(__bf16)v[0], (__bf16)v[1], (__bf16)v[2], (__bf16)v[3]};
        *(bf16x4*)(smem + x_off(tok, c4)) = pk;
    }
    __syncthreads();   // barrier 1: x staged

    // ===== Phase 1: head w's 96 channels (Q,K,V) x 64 tokens, K=128 =========
    // weight m-tiles for head w: Q: 2w,2w+1  K: 8+2w,8+2w+1  V: 16+2w,16+2w+1
    f32x4 acc[6][4];
    #pragma unroll
    for (int m = 0; m < 6; ++m)
        #pragma unroll
        for (int nt = 0; nt < 4; ++nt) acc[m][nt] = (f32x4){0.f, 0.f, 0.f, 0.f};

    #pragma unroll
    for (int ks = 0; ks < 4; ++ks) {
        bf16x8 xfr[4];
        #pragma unroll
        for (int nt = 0; nt < 4; ++nt)
            xfr[nt] = *(const bf16x8*)(smem + x_off(16 * nt + l16, 32 * ks + 8 * g));
        #pragma unroll
        for (int m = 0; m < 6; ++m) {
            int mtg = (m < 2) ? (2 * w + m) : (m < 4) ? (8 + 2 * w + m - 2)
                                                      : (16 + 2 * w + m - 4);
            bf16x8 af = *(const bf16x8*)(wpack + ((mtg * 4 + ks) * 64 + lane) * 8);
            #pragma unroll
            for (int nt = 0; nt < 4; ++nt)
                acc[m][nt] = __builtin_amdgcn_mfma_f32_16x16x32_bf16(af, xfr[nt], acc[m][nt], 0, 0, 0);
        }
    }

    // prefetch proj B-frags (wave w -> och tiles 2w, 2w+1)
    const __bf16* bp = wpack + 49152;
    bf16x8 bpf[2][4];
    #pragma unroll
    for (int ntp = 0; ntp < 2; ++ntp)
        #pragma unroll
        for (int ks = 0; ks < 4; ++ks)
            bpf[ntp][ks] = *(const bf16x8*)(bp + (((2 * w + ntp) * 4 + ks) * 64 + lane) * 8);

    // Q/K epilogue (own head region; x-buf untouched) — D: m=ch(4g+i), n=tok(16nt+l16)
    #pragma unroll
    for (int m = 0; m < 4; ++m) {
        const int gch = (m < 2) ? (32 * w + 16 * m + 4 * g)                 // Q global ch
                                : (128 + 32 * w + 16 * (m - 2) + 4 * g);    // K global ch
        const int lch = (m < 2) ? (16 * m + 4 * g) : (32 + 16 * (m - 2) + 4 * g);
        f32x4 bias = *(const f32x4*)(bqkv + gch);
        #pragma unroll
        for (int nt = 0; nt < 4; ++nt) {
            bf16x4 pk = {(__bf16)(acc[m][nt][0] + bias[0]), (__bf16)(acc[m][nt][1] + bias[1]),
                         (__bf16)(acc[m][nt][2] + bias[2]), (__bf16)(acc[m][nt][3] + bias[3])};
            *(bf16x4*)(smem + qk_off(w, 16 * nt + l16, lch)) = pk;
        }
    }
    __syncthreads();   // barrier 2: all x reads done -> x-buf becomes V^T

    // V epilogue into x-buf region (V accs held in regs across the barrier)
    #pragma unroll
    for (int m = 4; m < 6; ++m) {
        const int vch = 16 * (m - 4) + 4 * g;
        f32x4 bias = *(const f32x4*)(bqkv + 256 + 32 * w + vch);
        #pragma unroll
        for (int nt = 0; nt < 4; ++nt) {
            const int T = 16 * nt + l16;
            *(__bf16*)(smem + vt_off(w, vch + 0, T)) = (__bf16)(acc[m][nt][0] + bias[0]);
            *(__bf16*)(smem + vt_off(w, vch + 1, T)) = (__bf16)(acc[m][nt][1] + bias[1]);
            *(__bf16*)(smem + vt_off(w, vch + 2, T)) = (__bf16)(acc[m][nt][2] + bias[2]);
            *(__bf16*)(smem + vt_off(w, vch + 3, T)) = (__bf16)(acc[m][nt][3] + bias[3]);
        }
    }

    // ===== Phase 2a: S^T = K_h @ Q_h^T  (M=64 keys, N=64 q, K=32 ch) ========
    bf16x8 kf[4], qf[4];
    #pragma unroll
    for (int t = 0; t < 4; ++t) {
        kf[t] = *(const bf16x8*)(smem + qk_off(w, 16 * t + l16, 32 + 8 * g));
        qf[t] = *(const bf16x8*)(smem + qk_off(w, 16 * t + l16, 8 * g));
    }
    f32x4 s[4][4];
    #pragma unroll
    for (int mt = 0; mt < 4; ++mt)
        #pragma unroll
        for (int nt = 0; nt < 4; ++nt)
            s[mt][nt] = __builtin_amdgcn_mfma_f32_16x16x32_bf16(
                kf[mt], qf[nt], (f32x4){0.f, 0.f, 0.f, 0.f}, 0, 0, 0);

    // softmax over keys; lane holds keys {16mt+4g+i} for q = 16nt+l16
    constexpr float SC = 0.08838834764831845f * 1.4426950408889634f;  // scale*log2e
    #pragma unroll
    for (int nt = 0; nt < 4; ++nt) {
        float mx = -1e30f;
        #pragma unroll
        for (int mt = 0; mt < 4; ++mt)
            #pragma unroll
            for (int i = 0; i < 4; ++i) {
                int key = 16 * mt + 4 * g + i;
                if (key < N_TOK) mx = fmaxf(mx, s[mt][nt][i]);
            }
        mx = fmaxf(mx, __shfl_xor(mx, 16));
        mx = fmaxf(mx, __shfl_xor(mx, 32));
        float sum = 0.f;
        #pragma unroll
        for (int mt = 0; mt < 4; ++mt)
            #pragma unroll
            for (int i = 0; i < 4; ++i) {
                int key = 16 * mt + 4 * g + i;
                float p = (key < N_TOK) ? exp2f((s[mt][nt][i] - mx) * SC) : 0.f;
                s[mt][nt][i] = p;
                sum += p;
            }
        sum += __shfl_xor(sum, 16);
        sum += __shfl_xor(sum, 32);
        float r = 1.f / sum;
        #pragma unroll
        for (int mt = 0; mt < 4; ++mt)
            #pragma unroll
            for (int i = 0; i < 4; ++i) s[mt][nt][i] *= r;
    }

    // P[q][key] over the QK region (Q/K already consumed into regs by this wave)
    #pragma unroll
    for (int mt = 0; mt < 4; ++mt)
        #pragma unroll
        for (int nt = 0; nt < 4; ++nt) {
            bf16x4 pk = {(__bf16)s[mt][nt][0], (__bf16)s[mt][nt][1],
                         (__bf16)s[mt][nt][2], (__bf16)s[mt][nt][3]};
            *(bf16x4*)(smem + qk_off(w, 16 * nt + l16, 16 * mt + 4 * g)) = pk;
        }

    // ===== Phase 2b: O^T = V_h^T @ P^T  (M=32 ch, N=64 q, K=64 keys) ========
    bf16x8 vf[2][2], pf[4][2];
    #pragma unroll
    for (int ks = 0; ks < 2; ++ks) {
        #pragma unroll
        for (int m = 0; m < 2; ++m)
            vf[m][ks] = *(const bf16x8*)(smem + vt_off(w, 16 * m + l16, 32 * ks + 8 * g));
        #pragma unroll
        for (int nt = 0; nt < 4; ++nt)
            pf[nt][ks] = *(const bf16x8*)(smem + qk_off(w, 16 * nt + l16, 32 * ks + 8 * g));
    }
    f32x4 o[2][4];
    #pragma unroll
    for (int m = 0; m < 2; ++m)
        #pragma unroll
        for (int nt = 0; nt < 4; ++nt) o[m][nt] = (f32x4){0.f, 0.f, 0.f, 0.f};
    #pragma unroll
    for (int ks = 0; ks < 2; ++ks)
        #pragma unroll
        for (int m = 0; m < 2; ++m)
            #pragma unroll
            for (int nt = 0; nt < 4; ++nt)
                o[m][nt] = __builtin_amdgcn_mfma_f32_16x16x32_bf16(
                    vf[m][ks], pf[nt][ks], o[m][nt], 0, 0, 0);
    // O[q][ch32] aliases P rows — all pf reads already landed in regs.
    #pragma unroll
    for (int m = 0; m < 2; ++m)
        #pragma unroll
        for (int nt = 0; nt < 4; ++nt) {
            bf16x4 pk = {(__bf16)o[m][nt][0], (__bf16)o[m][nt][1],
                         (__bf16)o[m][nt][2], (__bf16)o[m][nt][3]};
            *(bf16x4*)(smem + o_off(w, 16 * nt + l16, 16 * m + 4 * g)) = pk;
        }
    __syncthreads();   // barrier 3: proj mixes all heads' O

    // ===== Phase 3: out = O @ Wproj + bproj; wave w owns och 32w..32w+31 ====
    f32x4 po[4][2];
    #pragma unroll
    for (int mt = 0; mt < 4; ++mt) {
        po[mt][0] = (f32x4){0.f, 0.f, 0.f, 0.f};
        po[mt][1] = (f32x4){0.f, 0.f, 0.f, 0.f};
    }
    #pragma unroll
    for (int ks = 0; ks < 4; ++ks) {   // ks = inch tile = head region
        #pragma unroll
        for (int mt = 0; mt < 4; ++mt) {
            bf16x8 a = *(const bf16x8*)(smem + o_off(ks, 16 * mt + l16, 8 * g));
            po[mt][0] = __builtin_amdgcn_mfma_f32_16x16x32_bf16(a, bpf[0][ks], po[mt][0], 0, 0, 0);
            po[mt][1] = __builtin_amdgcn_mfma_f32_16x16x32_bf16(a, bpf[1][ks], po[mt][1], 0, 0, 0);
        }
    }
    #pragma unroll
    for (int ntp = 0; ntp < 2; ++ntp) {
        const int och = 16 * (2 * w + ntp) + l16;
        const float bias = bproj[och];
        #pragma unroll
        for (int mt = 0; mt < 4; ++mt)
            #pragma unroll
            for (int i = 0; i < 4; ++i) {
                int tok = 16 * mt + 4 * g + i;
                if (tok < N_TOK)
                    out[((size_t)b * N_TOK + tok) * 128 + och] = po[mt][ntp][i] + bias;
            }
    }
}

extern "C" void kernel_launch(void* const* d_in, const int* in_sizes, int n_in,
                              void* d_out, int out_size, void* d_ws, size_t ws_size,
                              hipStream_t stream) {
    const float* x     = (const float*)d_in[0];
    const float* Wqkv  = (const float*)d_in[1];
    const float* bqkv  = (const float*)d_in[2];
    const float* Wproj = (const float*)d_in[3];
    const float* bproj = (const float*)d_in[4];
    __bf16* ws  = (__bf16*)d_ws;
    float* outp = (float*)d_out;

    pack_weights<<<256, 256, 0, stream>>>(Wqkv, Wproj, ws);
    fused_win_attn<<<4096, 256, 0, stream>>>(x, bqkv, bproj, ws, outp);
}